// Round 13
// baseline (277.134 us; speedup 1.0000x reference)
//
#include <hip/hip_runtime.h>

#define IN_SIZE 256
#define OUT_SIZE 64
#define BSHIFT 7         // 128-row buckets
#define BROWS 128
#define BMASK 127
#define CAP 2560         // bucket capacity: mean 2046, sigma 45 -> +11 sigma
#define K1_EDGES 4096    // edges per coarse block (16/thread at 256 threads)
#define WPAD 264         // 256+8 shorts

typedef __attribute__((ext_vector_type(8))) short short8;   // 8 bf16, 4 VGPRs
typedef __attribute__((ext_vector_type(4))) float floatx4;  // MFMA acc

__device__ inline unsigned short f2bf(float f) {
  unsigned u = __builtin_bit_cast(unsigned, f);
  u += 0x7fff + ((u >> 16) & 1);  // round-to-nearest-even
  return (unsigned short)(u >> 16);
}
__device__ inline float bf2f(unsigned short u) {
  unsigned v = (unsigned)u << 16;
  return __builtin_bit_cast(float, v);
}

// ---------------------------------------------------------------------------
// K0: zero the coarse cursors.
__global__ __launch_bounds__(512) void zero_kernel(int* __restrict__ cursor) {
  int i = blockIdx.x * 512 + threadIdx.x;
  if (i < 1024) cursor[i] = 0;
}

// ---------------------------------------------------------------------------
// R13 DIAGNOSTIC SPLIT: the heterogeneous fused1 gave one merged PMC row for
// two different programs; 4 rounds of theories about "which path is slow"
// were all refuted (r9 MLP null, r11 chain null, r12 LDS-residency null).
// This round separates them for per-kernel counters, accepting the loss of
// overlap (~15us) to learn where the ~57-69us actually lives.

// K1a: coarse bucketing, standalone (r12 path: 256 thr, 16 edges/thread).
__global__ __launch_bounds__(256) void coarse_kernel(
    const int* __restrict__ row, const int* __restrict__ col,
    int* __restrict__ coarse_cursor, unsigned* __restrict__ pairs,
    int n_edges, int nbuck) {
  __shared__ int hist[1024];  // nbuck=782 <= 1024
  int tid = threadIdx.x;
  int bid = blockIdx.x;

#pragma unroll
  for (int i = 0; i < 4; i++) hist[tid + i * 256] = 0;
  __syncthreads();

  int r[16], c[16];
  int ebase = bid * K1_EDGES + tid;
#pragma unroll
  for (int i = 0; i < 16; i++) {
    int e = ebase + i * 256;
    bool ok = e < n_edges;
    r[i] = ok ? row[e] : -1;
    c[i] = ok ? col[e] : -1;
    if (ok && r[i] != c[i]) atomicAdd(&hist[r[i] >> BSHIFT], 1);
  }
  __syncthreads();

  for (int i = tid; i < nbuck; i += 256) {
    int cnt = hist[i];
    if (cnt) hist[i] = atomicAdd(&coarse_cursor[i], cnt);
  }
  __syncthreads();

#pragma unroll
  for (int i = 0; i < 16; i++) {
    if (r[i] >= 0 && r[i] != c[i]) {
      int bin = r[i] >> BSHIFT;
      int slot = atomicAdd(&hist[bin], 1);
      if (slot < CAP)
        pairs[(size_t)bin * CAP + slot] =
            ((unsigned)(r[i] & BMASK) << 17) | (unsigned)c[i];
    }
  }
}

// K1b: matmul, standalone (r3's proven body: 512 thr, W fp32->bf16 staged to
// LDS once per block, 128 rows/block, NO dinv).
__global__ __launch_bounds__(512) void matmul_kernel(
    const float* __restrict__ x, const float* __restrict__ W,
    unsigned short* __restrict__ xwb, int n_nodes) {
  __shared__ unsigned short w_lds[64 * WPAD];
  int tid = threadIdx.x;
  long nbase = (long)blockIdx.x * 128;
  {
    int r = tid >> 3;  // 0..63
    int q = tid & 7;   // 8 chunks of 32 floats
    const float* src = W + (size_t)r * IN_SIZE + q * 32;
#pragma unroll
    for (int i = 0; i < 4; i++) {
      float4 a = *(const float4*)(src + i * 8);
      float4 b = *(const float4*)(src + i * 8 + 4);
      short8 s;
      s[0] = (short)f2bf(a.x); s[1] = (short)f2bf(a.y);
      s[2] = (short)f2bf(a.z); s[3] = (short)f2bf(a.w);
      s[4] = (short)f2bf(b.x); s[5] = (short)f2bf(b.y);
      s[6] = (short)f2bf(b.z); s[7] = (short)f2bf(b.w);
      *(short8*)(&w_lds[r * WPAD + q * 32 + i * 8]) = s;
    }
  }
  __syncthreads();

  int wave = tid >> 6;
  int lane = tid & 63;
  int quad = lane >> 4;
  int lcol = lane & 15;
  long node = nbase + wave * 16 + lcol;
  long nclamp = (node < (long)n_nodes) ? node : (long)(n_nodes - 1);
  const float* xrow = x + nclamp * IN_SIZE;

  floatx4 acc[4];
#pragma unroll
  for (int t = 0; t < 4; t++) acc[t] = (floatx4){0.f, 0.f, 0.f, 0.f};

#pragma unroll
  for (int kk = 0; kk < 8; kk++) {
    const float* p = xrow + kk * 32 + quad * 8;
    float4 a = *(const float4*)(p);
    float4 bb = *(const float4*)(p + 4);
    short8 bfrag;
    bfrag[0] = (short)f2bf(a.x);  bfrag[1] = (short)f2bf(a.y);
    bfrag[2] = (short)f2bf(a.z);  bfrag[3] = (short)f2bf(a.w);
    bfrag[4] = (short)f2bf(bb.x); bfrag[5] = (short)f2bf(bb.y);
    bfrag[6] = (short)f2bf(bb.z); bfrag[7] = (short)f2bf(bb.w);
#pragma unroll
    for (int t = 0; t < 4; t++) {
      short8 afrag =
          *(const short8*)(&w_lds[(t * 16 + lcol) * WPAD + kk * 32 + quad * 8]);
      acc[t] = __builtin_amdgcn_mfma_f32_16x16x32_bf16(afrag, bfrag, acc[t],
                                                       0, 0, 0);
    }
  }

  if (node < (long)n_nodes) {
#pragma unroll
    for (int t = 0; t < 4; t++) {
      ushort4 sv;
      sv.x = f2bf(acc[t][0]);
      sv.y = f2bf(acc[t][1]);
      sv.z = f2bf(acc[t][2]);
      sv.w = f2bf(acc[t][3]);
      *(ushort4*)(xwb + node * OUT_SIZE + t * 16 + quad * 4) = sv;
    }
  }
}

// ---------------------------------------------------------------------------
// K2: fine CSR build, single-pass (512 threads; r0/r3 structure).
__global__ __launch_bounds__(512) void fine_kernel(
    const int* __restrict__ coarse_cursor, const unsigned* __restrict__ pairs,
    unsigned* __restrict__ colsp, int* __restrict__ count,
    int* __restrict__ row_start, float* __restrict__ dinv, int n_nodes) {
  __shared__ unsigned lpair[CAP];  // 10 KB
  __shared__ int hist[BROWS];
  __shared__ int scn[BROWS];
  int tid = threadIdx.x;
  int b = blockIdx.x;
  size_t base = (size_t)b * CAP;
  int n_b = coarse_cursor[b];
  if (n_b > CAP) n_b = CAP;

  if (tid < BROWS) hist[tid] = 0;
  __syncthreads();

  for (int i = tid; i < n_b; i += 512) {  // copy + histogram in one pass
    unsigned p = pairs[base + i];
    lpair[i] = p;
    atomicAdd(&hist[p >> 17], 1);
  }
  __syncthreads();

  if (tid < BROWS) scn[tid] = hist[tid];
  __syncthreads();
  for (int off = 1; off < BROWS; off <<= 1) {
    int t = (tid >= off && tid < BROWS) ? scn[tid - off] : 0;
    __syncthreads();
    if (tid < BROWS) scn[tid] += t;
    __syncthreads();
  }

  if (tid < BROWS) {
    int e = (tid > 0) ? scn[tid - 1] : 0;
    int r = b * BROWS + tid;
    if (r < n_nodes) {
      int deg = hist[tid];
      count[r] = deg;
      row_start[r] = (int)base + e;
      dinv[r] = rsqrtf((float)deg + 1.0f);
    }
    hist[tid] = e;  // becomes scatter cursor
  }
  __syncthreads();

  for (int i = tid; i < n_b; i += 512) {
    unsigned p = lpair[i];
    int slot = atomicAdd(&hist[p >> 17], 1);
    colsp[base + slot] = p & 0x1FFFFu;
  }
}

// ---------------------------------------------------------------------------
// K3: CSR gather -- round-3 structure VERBATIM (proven 65-66us local optimum:
// full 128B row per edge, 8 slots x 8 cg, 4 rows/wave, 48 VGPR, occ 45%).
// Refuted: 2-edge unroll (r4), SW prefetch (r6: compiler no-op),
// channel-half split (r7: FETCH x2).
__global__ __launch_bounds__(256) void gather_kernel(
    const int* __restrict__ row_start, const int* __restrict__ count,
    const unsigned* __restrict__ colsp, const float* __restrict__ dinv,
    const unsigned short* __restrict__ xwb, float* __restrict__ out,
    int n_nodes) {
  int lane = threadIdx.x & 63;
  int wave = threadIdx.x >> 6;
  int sub = lane & 7;   // edge slot
  int cg = lane >> 3;   // channels cg*8 .. cg*8+7
  int rb = (blockIdx.x * 4 + wave) * 4;  // first of 4 rows
  if (rb >= n_nodes) return;

  int start[4], cnt[4];
  int maxc = 0;
#pragma unroll
  for (int i = 0; i < 4; i++) {
    int r = rb + i;
    bool ok = r < n_nodes;
    start[i] = ok ? row_start[r] : 0;
    cnt[i] = ok ? count[r] : 0;
    maxc = max(maxc, cnt[i]);
  }

  float acc[4][8];
#pragma unroll
  for (int i = 0; i < 4; i++)
#pragma unroll
    for (int k = 0; k < 8; k++) acc[i][k] = 0.f;

  if (sub == 0) {  // self-loop terms: dinv[r]*xw[r]
#pragma unroll
    for (int i = 0; i < 4; i++) {
      int r = rb + i;
      if (r < n_nodes) {
        float dv = dinv[r];
        short8 v = *(const short8*)(xwb + (size_t)r * OUT_SIZE + cg * 8);
#pragma unroll
        for (int k = 0; k < 8; k++) acc[i][k] = dv * bf2f((unsigned short)v[k]);
      }
    }
  }

  for (int j = 0; j < maxc; j += 8) {
    int c[4];
    float m[4];
    int idx = j + sub;
#pragma unroll
    for (int i = 0; i < 4; i++) {
      bool act = idx < cnt[i];
      c[i] = act ? (int)colsp[start[i] + idx] : rb;  // dummy -> hot line
      m[i] = act ? dinv[c[i]] : 0.0f;
    }
    short8 v[4];
#pragma unroll
    for (int i = 0; i < 4; i++)
      v[i] = *(const short8*)(xwb + (size_t)c[i] * OUT_SIZE + cg * 8);
#pragma unroll
    for (int i = 0; i < 4; i++)
#pragma unroll
      for (int k = 0; k < 8; k++)
        acc[i][k] += m[i] * bf2f((unsigned short)v[i][k]);
  }

#pragma unroll
  for (int i = 0; i < 4; i++)
#pragma unroll
    for (int k = 0; k < 8; k++) {
      acc[i][k] += __shfl_xor(acc[i][k], 1);
      acc[i][k] += __shfl_xor(acc[i][k], 2);
      acc[i][k] += __shfl_xor(acc[i][k], 4);
    }

  if (sub == 0) {
#pragma unroll
    for (int i = 0; i < 4; i++) {
      int r = rb + i;
      if (r < n_nodes) {
        float dr = dinv[r];
        float* dst = out + (size_t)r * OUT_SIZE + cg * 8;
        *(float4*)(dst) =
            make_float4(dr * acc[i][0], dr * acc[i][1], dr * acc[i][2],
                        dr * acc[i][3]);
        *(float4*)(dst + 4) =
            make_float4(dr * acc[i][4], dr * acc[i][5], dr * acc[i][6],
                        dr * acc[i][7]);
      }
    }
  }
}

// ---------------------------------------------------------------------------
extern "C" void kernel_launch(void* const* d_in, const int* in_sizes, int n_in,
                              void* d_out, int out_size, void* d_ws,
                              size_t ws_size, hipStream_t stream) {
  const int* edge_index = (const int*)d_in[0];
  const float* x = (const float*)d_in[1];
  const float* W = (const float*)d_in[3];

  int n_edges = in_sizes[0] / 2;
  int n_nodes = in_sizes[1] / IN_SIZE;
  const int* row = edge_index;
  const int* col = edge_index + n_edges;
  float* out = (float*)d_out;

  int nbuck = (n_nodes + BROWS - 1) >> BSHIFT;          // 782
  int nb_coarse = (n_edges + K1_EDGES - 1) / K1_EDGES;  // 391
  int nb_mm = (n_nodes + 127) / 128;                    // 782

  // Workspace: count[N] | row_start[N] | dinv[N] | coarse_cursor(4KB) |
  //            pairs[nbuck*CAP u32] | colsp[nbuck*CAP u32] | xwb[N*64 bf16]
  char* ws = (char*)d_ws;
  size_t nb4 = ((size_t)n_nodes * 4 + 15) & ~(size_t)15;
  int* count = (int*)ws;
  int* row_start = (int*)(ws + nb4);
  float* dinv = (float*)(ws + 2 * nb4);
  int* coarse_cursor = (int*)(ws + 3 * nb4);
  size_t pairsB = (size_t)nbuck * CAP * 4;  // 8,007,680 B
  unsigned* pairs = (unsigned*)(ws + 3 * nb4 + 4096);
  unsigned* colsp = (unsigned*)(ws + 3 * nb4 + 4096 + pairsB);
  unsigned short* xwb =
      (unsigned short*)(ws + 3 * nb4 + 4096 + 2 * pairsB);

  zero_kernel<<<2, 512, 0, stream>>>(coarse_cursor);
  coarse_kernel<<<nb_coarse, 256, 0, stream>>>(row, col, coarse_cursor,
                                               pairs, n_edges, nbuck);
  matmul_kernel<<<nb_mm, 512, 0, stream>>>(x, W, xwb, n_nodes);
  fine_kernel<<<nbuck, 512, 0, stream>>>(coarse_cursor, pairs, colsp, count,
                                         row_start, dinv, n_nodes);
  gather_kernel<<<(n_nodes + 15) / 16, 256, 0, stream>>>(
      row_start, count, colsp, dinv, xwb, out, n_nodes);
}

// Round 14
// 274.491 us; speedup vs baseline: 1.0096x; 1.0096x over previous
//
#include <hip/hip_runtime.h>

#define IN_SIZE 256
#define OUT_SIZE 64
#define BSHIFT 7         // 128-row buckets
#define BROWS 128
#define BMASK 127
#define CAP 2560         // bucket capacity: mean 2046, sigma 45 -> +11 sigma
#define K1_EDGES 4096    // edges per coarse block (16/thread at 256 threads)
#define WPAD 266         // 133 dwords = 5 mod 32 -> ~2-way b128 conflicts
#define MMROWS 64        // nodes per matmul block (4 waves x 16 rows)

typedef __attribute__((ext_vector_type(8))) short short8;   // 8 bf16, 4 VGPRs
typedef __attribute__((ext_vector_type(4))) float floatx4;  // MFMA acc

__device__ inline unsigned short f2bf(float f) {
  unsigned u = __builtin_bit_cast(unsigned, f);
  u += 0x7fff + ((u >> 16) & 1);  // round-to-nearest-even
  return (unsigned short)(u >> 16);
}
__device__ inline float bf2f(unsigned short u) {
  unsigned v = (unsigned)u << 16;
  return __builtin_bit_cast(float, v);
}

// ---------------------------------------------------------------------------
// K0: zero the coarse cursors.
__global__ __launch_bounds__(512) void zero_kernel(int* __restrict__ cursor) {
  int i = blockIdx.x * 512 + threadIdx.x;
  if (i < 1024) cursor[i] = 0;
}

// ---------------------------------------------------------------------------
// K1a: coarse bucketing, standalone (r13 shape; deduced ~21us, short pole).
__global__ __launch_bounds__(256) void coarse_kernel(
    const int* __restrict__ row, const int* __restrict__ col,
    int* __restrict__ coarse_cursor, unsigned* __restrict__ pairs,
    int n_edges, int nbuck) {
  __shared__ int hist[1024];  // nbuck=782 <= 1024
  int tid = threadIdx.x;
  int bid = blockIdx.x;

#pragma unroll
  for (int i = 0; i < 4; i++) hist[tid + i * 256] = 0;
  __syncthreads();

  int r[16], c[16];
  int ebase = bid * K1_EDGES + tid;
#pragma unroll
  for (int i = 0; i < 16; i++) {
    int e = ebase + i * 256;
    bool ok = e < n_edges;
    r[i] = ok ? row[e] : -1;
    c[i] = ok ? col[e] : -1;
    if (ok && r[i] != c[i]) atomicAdd(&hist[r[i] >> BSHIFT], 1);
  }
  __syncthreads();

  for (int i = tid; i < nbuck; i += 256) {
    int cnt = hist[i];
    if (cnt) hist[i] = atomicAdd(&coarse_cursor[i], cnt);
  }
  __syncthreads();

#pragma unroll
  for (int i = 0; i < 16; i++) {
    if (r[i] >= 0 && r[i] != c[i]) {
      int bin = r[i] >> BSHIFT;
      int slot = atomicAdd(&hist[bin], 1);
      if (slot < CAP)
        pairs[(size_t)bin * CAP + slot] =
            ((unsigned)(r[i] & BMASK) << 17) | (unsigned)c[i];
    }
  }
}

// ---------------------------------------------------------------------------
// K1b: matmul with the MLP fix. r13 deduction: matmul is the ~57us pole at
// VGPR=32 -- compiler recycles load regs, only ~2 kk-iters of x in flight,
// 102MB crawls at 1.8 TB/s. Fix: 256-thr blocks (64 rows, 1563 blocks),
// preload the FULL per-lane x slice (16 float4 = 64 VGPR) BEFORE the W-stage
// (x HBM latency hides under stage+barrier), MFMA from registers. LDS 34KB
// caps occupancy at 4 blocks x 4 waves = 16 waves/CU, so the px VGPRs are
// free (unlike r9's 512-thr merged attempt where they halved waves/CU).
__global__ __launch_bounds__(256) void matmul_kernel(
    const float* __restrict__ x, const float* __restrict__ W,
    unsigned short* __restrict__ xwb, int n_nodes) {
  __shared__ unsigned short w_lds[64 * WPAD];  // 34 KB
  int tid = threadIdx.x;
  int wave = tid >> 6;
  int lane = tid & 63;
  int quad = lane >> 4;
  int lcol = lane & 15;
  long node = (long)blockIdx.x * MMROWS + wave * 16 + lcol;
  long nclamp = (node < (long)n_nodes) ? node : (long)(n_nodes - 1);
  const float* xrow = x + nclamp * IN_SIZE;

  // (1) issue ALL x loads first -- 256B/lane outstanding.
  float4 px[16];
#pragma unroll
  for (int kk = 0; kk < 8; kk++) {
    const float* p = xrow + kk * 32 + quad * 8;
    px[2 * kk] = *(const float4*)(p);
    px[2 * kk + 1] = *(const float4*)(p + 4);
  }

  // (2) stage W (fp32->bf16) to LDS while x loads are in flight.
  {
    int r = tid >> 2;        // 0..63
    int q = (tid & 3) * 64;  // 64-short chunk
    const float* src = W + (size_t)r * IN_SIZE + q;
#pragma unroll
    for (int i = 0; i < 8; i++) {
      float4 a = *(const float4*)(src + i * 8);
      float4 b = *(const float4*)(src + i * 8 + 4);
      short8 s;
      s[0] = (short)f2bf(a.x); s[1] = (short)f2bf(a.y);
      s[2] = (short)f2bf(a.z); s[3] = (short)f2bf(a.w);
      s[4] = (short)f2bf(b.x); s[5] = (short)f2bf(b.y);
      s[6] = (short)f2bf(b.z); s[7] = (short)f2bf(b.w);
      *(short8*)(&w_lds[r * WPAD + q + i * 8]) = s;
    }
  }
  __syncthreads();

  // (3) MFMA from registers + LDS.
  floatx4 acc[4];
#pragma unroll
  for (int t = 0; t < 4; t++) acc[t] = (floatx4){0.f, 0.f, 0.f, 0.f};

#pragma unroll
  for (int kk = 0; kk < 8; kk++) {
    float4 a = px[2 * kk];
    float4 bb = px[2 * kk + 1];
    short8 bfrag;
    bfrag[0] = (short)f2bf(a.x);  bfrag[1] = (short)f2bf(a.y);
    bfrag[2] = (short)f2bf(a.z);  bfrag[3] = (short)f2bf(a.w);
    bfrag[4] = (short)f2bf(bb.x); bfrag[5] = (short)f2bf(bb.y);
    bfrag[6] = (short)f2bf(bb.z); bfrag[7] = (short)f2bf(bb.w);
#pragma unroll
    for (int t = 0; t < 4; t++) {
      short8 afrag =
          *(const short8*)(&w_lds[(t * 16 + lcol) * WPAD + kk * 32 + quad * 8]);
      acc[t] = __builtin_amdgcn_mfma_f32_16x16x32_bf16(afrag, bfrag, acc[t],
                                                       0, 0, 0);
    }
  }

  if (node < (long)n_nodes) {
#pragma unroll
    for (int t = 0; t < 4; t++) {
      ushort4 sv;
      sv.x = f2bf(acc[t][0]);
      sv.y = f2bf(acc[t][1]);
      sv.z = f2bf(acc[t][2]);
      sv.w = f2bf(acc[t][3]);
      *(ushort4*)(xwb + node * OUT_SIZE + t * 16 + quad * 4) = sv;
    }
  }
}

// ---------------------------------------------------------------------------
// K2: fine CSR build, single-pass (512 threads; r0/r3 structure).
__global__ __launch_bounds__(512) void fine_kernel(
    const int* __restrict__ coarse_cursor, const unsigned* __restrict__ pairs,
    unsigned* __restrict__ colsp, int* __restrict__ count,
    int* __restrict__ row_start, float* __restrict__ dinv, int n_nodes) {
  __shared__ unsigned lpair[CAP];  // 10 KB
  __shared__ int hist[BROWS];
  __shared__ int scn[BROWS];
  int tid = threadIdx.x;
  int b = blockIdx.x;
  size_t base = (size_t)b * CAP;
  int n_b = coarse_cursor[b];
  if (n_b > CAP) n_b = CAP;

  if (tid < BROWS) hist[tid] = 0;
  __syncthreads();

  for (int i = tid; i < n_b; i += 512) {  // copy + histogram in one pass
    unsigned p = pairs[base + i];
    lpair[i] = p;
    atomicAdd(&hist[p >> 17], 1);
  }
  __syncthreads();

  if (tid < BROWS) scn[tid] = hist[tid];
  __syncthreads();
  for (int off = 1; off < BROWS; off <<= 1) {
    int t = (tid >= off && tid < BROWS) ? scn[tid - off] : 0;
    __syncthreads();
    if (tid < BROWS) scn[tid] += t;
    __syncthreads();
  }

  if (tid < BROWS) {
    int e = (tid > 0) ? scn[tid - 1] : 0;
    int r = b * BROWS + tid;
    if (r < n_nodes) {
      int deg = hist[tid];
      count[r] = deg;
      row_start[r] = (int)base + e;
      dinv[r] = rsqrtf((float)deg + 1.0f);
    }
    hist[tid] = e;  // becomes scatter cursor
  }
  __syncthreads();

  for (int i = tid; i < n_b; i += 512) {
    unsigned p = lpair[i];
    int slot = atomicAdd(&hist[p >> 17], 1);
    colsp[base + slot] = p & 0x1FFFFu;
  }
}

// ---------------------------------------------------------------------------
// K3: CSR gather -- round-3 structure VERBATIM (proven 65-66us local optimum:
// full 128B row per edge, 8 slots x 8 cg, 4 rows/wave, 48 VGPR, occ 45%).
// Refuted: 2-edge unroll (r4), SW prefetch (r6: compiler no-op),
// channel-half split (r7: FETCH x2).
__global__ __launch_bounds__(256) void gather_kernel(
    const int* __restrict__ row_start, const int* __restrict__ count,
    const unsigned* __restrict__ colsp, const float* __restrict__ dinv,
    const unsigned short* __restrict__ xwb, float* __restrict__ out,
    int n_nodes) {
  int lane = threadIdx.x & 63;
  int wave = threadIdx.x >> 6;
  int sub = lane & 7;   // edge slot
  int cg = lane >> 3;   // channels cg*8 .. cg*8+7
  int rb = (blockIdx.x * 4 + wave) * 4;  // first of 4 rows
  if (rb >= n_nodes) return;

  int start[4], cnt[4];
  int maxc = 0;
#pragma unroll
  for (int i = 0; i < 4; i++) {
    int r = rb + i;
    bool ok = r < n_nodes;
    start[i] = ok ? row_start[r] : 0;
    cnt[i] = ok ? count[r] : 0;
    maxc = max(maxc, cnt[i]);
  }

  float acc[4][8];
#pragma unroll
  for (int i = 0; i < 4; i++)
#pragma unroll
    for (int k = 0; k < 8; k++) acc[i][k] = 0.f;

  if (sub == 0) {  // self-loop terms: dinv[r]*xw[r]
#pragma unroll
    for (int i = 0; i < 4; i++) {
      int r = rb + i;
      if (r < n_nodes) {
        float dv = dinv[r];
        short8 v = *(const short8*)(xwb + (size_t)r * OUT_SIZE + cg * 8);
#pragma unroll
        for (int k = 0; k < 8; k++) acc[i][k] = dv * bf2f((unsigned short)v[k]);
      }
    }
  }

  for (int j = 0; j < maxc; j += 8) {
    int c[4];
    float m[4];
    int idx = j + sub;
#pragma unroll
    for (int i = 0; i < 4; i++) {
      bool act = idx < cnt[i];
      c[i] = act ? (int)colsp[start[i] + idx] : rb;  // dummy -> hot line
      m[i] = act ? dinv[c[i]] : 0.0f;
    }
    short8 v[4];
#pragma unroll
    for (int i = 0; i < 4; i++)
      v[i] = *(const short8*)(xwb + (size_t)c[i] * OUT_SIZE + cg * 8);
#pragma unroll
    for (int i = 0; i < 4; i++)
#pragma unroll
      for (int k = 0; k < 8; k++)
        acc[i][k] += m[i] * bf2f((unsigned short)v[i][k]);
  }

#pragma unroll
  for (int i = 0; i < 4; i++)
#pragma unroll
    for (int k = 0; k < 8; k++) {
      acc[i][k] += __shfl_xor(acc[i][k], 1);
      acc[i][k] += __shfl_xor(acc[i][k], 2);
      acc[i][k] += __shfl_xor(acc[i][k], 4);
    }

  if (sub == 0) {
#pragma unroll
    for (int i = 0; i < 4; i++) {
      int r = rb + i;
      if (r < n_nodes) {
        float dr = dinv[r];
        float* dst = out + (size_t)r * OUT_SIZE + cg * 8;
        *(float4*)(dst) =
            make_float4(dr * acc[i][0], dr * acc[i][1], dr * acc[i][2],
                        dr * acc[i][3]);
        *(float4*)(dst + 4) =
            make_float4(dr * acc[i][4], dr * acc[i][5], dr * acc[i][6],
                        dr * acc[i][7]);
      }
    }
  }
}

// ---------------------------------------------------------------------------
extern "C" void kernel_launch(void* const* d_in, const int* in_sizes, int n_in,
                              void* d_out, int out_size, void* d_ws,
                              size_t ws_size, hipStream_t stream) {
  const int* edge_index = (const int*)d_in[0];
  const float* x = (const float*)d_in[1];
  const float* W = (const float*)d_in[3];

  int n_edges = in_sizes[0] / 2;
  int n_nodes = in_sizes[1] / IN_SIZE;
  const int* row = edge_index;
  const int* col = edge_index + n_edges;
  float* out = (float*)d_out;

  int nbuck = (n_nodes + BROWS - 1) >> BSHIFT;          // 782
  int nb_coarse = (n_edges + K1_EDGES - 1) / K1_EDGES;  // 391
  int nb_mm = (n_nodes + MMROWS - 1) / MMROWS;          // 1563

  // Workspace: count[N] | row_start[N] | dinv[N] | coarse_cursor(4KB) |
  //            pairs[nbuck*CAP u32] | colsp[nbuck*CAP u32] | xwb[N*64 bf16]
  char* ws = (char*)d_ws;
  size_t nb4 = ((size_t)n_nodes * 4 + 15) & ~(size_t)15;
  int* count = (int*)ws;
  int* row_start = (int*)(ws + nb4);
  float* dinv = (float*)(ws + 2 * nb4);
  int* coarse_cursor = (int*)(ws + 3 * nb4);
  size_t pairsB = (size_t)nbuck * CAP * 4;  // 8,007,680 B
  unsigned* pairs = (unsigned*)(ws + 3 * nb4 + 4096);
  unsigned* colsp = (unsigned*)(ws + 3 * nb4 + 4096 + pairsB);
  unsigned short* xwb =
      (unsigned short*)(ws + 3 * nb4 + 4096 + 2 * pairsB);

  zero_kernel<<<2, 512, 0, stream>>>(coarse_cursor);
  matmul_kernel<<<nb_mm, 256, 0, stream>>>(x, W, xwb, n_nodes);
  coarse_kernel<<<nb_coarse, 256, 0, stream>>>(row, col, coarse_cursor,
                                               pairs, n_edges, nbuck);
  fine_kernel<<<nbuck, 512, 0, stream>>>(coarse_cursor, pairs, colsp, count,
                                         row_start, dinv, n_nodes);
  gather_kernel<<<(n_nodes + 15) / 16, 256, 0, stream>>>(
      row_start, count, colsp, dinv, xwb, out, n_nodes);
}

// Round 15
// 248.184 us; speedup vs baseline: 1.1166x; 1.1060x over previous
//
#include <hip/hip_runtime.h>

#define IN_SIZE 256
#define OUT_SIZE 64
#define BSHIFT 7         // 128-row buckets
#define BROWS 128
#define BMASK 127
#define CAP 2560         // bucket capacity: mean 2046, sigma 45 -> +11 sigma
#define K1_EDGES 4096    // edges per coarse block (8/thread at 512 threads)
#define WPAD 264         // 256+8 shorts

typedef __attribute__((ext_vector_type(8))) short short8;   // 8 bf16, 4 VGPRs
typedef __attribute__((ext_vector_type(4))) float floatx4;  // MFMA acc

__device__ inline unsigned short f2bf(float f) {
  unsigned u = __builtin_bit_cast(unsigned, f);
  u += 0x7fff + ((u >> 16) & 1);  // round-to-nearest-even
  return (unsigned short)(u >> 16);
}
__device__ inline float bf2f(unsigned short u) {
  unsigned v = (unsigned)u << 16;
  return __builtin_bit_cast(float, v);
}

// ---------------------------------------------------------------------------
// K0: zero the coarse cursors.
__global__ __launch_bounds__(512) void zero_kernel(int* __restrict__ cursor) {
  int i = blockIdx.x * 512 + threadIdx.x;
  if (i < 1024) cursor[i] = 0;
}

// ---------------------------------------------------------------------------
// K1: heterogeneous merged grid -- the r11 config verbatim (best measured:
// 254.6 total, fused1 ~57us). r13/r14 serial split measured coarse+matmul
// ~75-78us; the merge buys ~20us of overlap (all 978+ blocks co-resident).
// Matmul stays dinv-FREE (that independence is what allows the merge);
// dinv is folded into xwb afterwards by fine_kernel.
struct K1SM {
  union {
    int hist[1024];                 // coarse path (nbuck=782 <= 1024)
    unsigned short w[64 * WPAD];    // matmul path: W tile bf16 (33.8 KB)
  };
};

__global__ __launch_bounds__(512) void fused1_kernel(
    const int* __restrict__ row, const int* __restrict__ col,
    int* __restrict__ coarse_cursor, unsigned* __restrict__ pairs,
    const float* __restrict__ x, const float* __restrict__ W,
    unsigned short* __restrict__ xwb, int n_edges, int n_nodes, int nbuck,
    int nb_coarse) {
  __shared__ K1SM sm;
  int tid = threadIdx.x;
  int bid = blockIdx.x;

  if (bid < nb_coarse) {
    // ---- coarse bucketing: 4096 edges, 8 per thread ----
    sm.hist[tid] = 0;
    sm.hist[tid + 512] = 0;
    __syncthreads();

    int r[8], c[8];
    int ebase = bid * K1_EDGES + tid;
#pragma unroll
    for (int i = 0; i < 8; i++) {
      int e = ebase + i * 512;
      bool ok = e < n_edges;
      r[i] = ok ? row[e] : -1;
      c[i] = ok ? col[e] : -1;
      if (ok && r[i] != c[i]) atomicAdd(&sm.hist[r[i] >> BSHIFT], 1);
    }
    __syncthreads();

    for (int i = tid; i < nbuck; i += 512) {
      int cnt = sm.hist[i];
      if (cnt) sm.hist[i] = atomicAdd(&coarse_cursor[i], cnt);
    }
    __syncthreads();

#pragma unroll
    for (int i = 0; i < 8; i++) {
      if (r[i] >= 0 && r[i] != c[i]) {
        int bin = r[i] >> BSHIFT;
        int slot = atomicAdd(&sm.hist[bin], 1);
        if (slot < CAP)
          pairs[(size_t)bin * CAP + slot] =
              ((unsigned)(r[i] & BMASK) << 17) | (unsigned)c[i];
      }
    }
  } else {
    // ---- matmul: 128 nodes per block, round-3 body verbatim ----
    int mb = bid - nb_coarse;
    long nbase = (long)mb * 128;
    {
      int r = tid >> 3;  // 0..63
      int q = tid & 7;   // 8 chunks of 32 floats
      const float* src = W + (size_t)r * IN_SIZE + q * 32;
#pragma unroll
      for (int i = 0; i < 4; i++) {
        float4 a = *(const float4*)(src + i * 8);
        float4 b = *(const float4*)(src + i * 8 + 4);
        short8 s;
        s[0] = (short)f2bf(a.x); s[1] = (short)f2bf(a.y);
        s[2] = (short)f2bf(a.z); s[3] = (short)f2bf(a.w);
        s[4] = (short)f2bf(b.x); s[5] = (short)f2bf(b.y);
        s[6] = (short)f2bf(b.z); s[7] = (short)f2bf(b.w);
        *(short8*)(&sm.w[r * WPAD + q * 32 + i * 8]) = s;
      }
    }
    __syncthreads();

    int wave = tid >> 6;
    int lane = tid & 63;
    int quad = lane >> 4;
    int lcol = lane & 15;
    long node = nbase + wave * 16 + lcol;
    long nclamp = (node < (long)n_nodes) ? node : (long)(n_nodes - 1);
    const float* xrow = x + nclamp * IN_SIZE;

    floatx4 acc[4];
#pragma unroll
    for (int t = 0; t < 4; t++) acc[t] = (floatx4){0.f, 0.f, 0.f, 0.f};

#pragma unroll
    for (int kk = 0; kk < 8; kk++) {
      const float* p = xrow + kk * 32 + quad * 8;
      float4 a = *(const float4*)(p);
      float4 bb = *(const float4*)(p + 4);
      short8 bfrag;
      bfrag[0] = (short)f2bf(a.x);  bfrag[1] = (short)f2bf(a.y);
      bfrag[2] = (short)f2bf(a.z);  bfrag[3] = (short)f2bf(a.w);
      bfrag[4] = (short)f2bf(bb.x); bfrag[5] = (short)f2bf(bb.y);
      bfrag[6] = (short)f2bf(bb.z); bfrag[7] = (short)f2bf(bb.w);
#pragma unroll
      for (int t = 0; t < 4; t++) {
        short8 afrag =
            *(const short8*)(&sm.w[(t * 16 + lcol) * WPAD + kk * 32 + quad * 8]);
        acc[t] = __builtin_amdgcn_mfma_f32_16x16x32_bf16(afrag, bfrag, acc[t],
                                                         0, 0, 0);
      }
    }

    if (node < (long)n_nodes) {
#pragma unroll
      for (int t = 0; t < 4; t++) {
        ushort4 sv;
        sv.x = f2bf(acc[t][0]);
        sv.y = f2bf(acc[t][1]);
        sv.z = f2bf(acc[t][2]);
        sv.w = f2bf(acc[t][3]);
        *(ushort4*)(xwb + node * OUT_SIZE + t * 16 + quad * 4) = sv;
      }
    }
  }
}

// ---------------------------------------------------------------------------
// K2: fine CSR build (512 thr) + NEW: scale this bucket's 128 xwb rows by
// dinv[r] in place. Evidence (r0 vs r3 family): gather WITHOUT the per-edge
// dinv[c] load runs <=59.6us vs 65.5-66.5 with it (~6us saved); the scaling
// costs ~25MB coalesced traffic here (~+4us on fine, partly hidden).
__global__ __launch_bounds__(512) void fine_kernel(
    const int* __restrict__ coarse_cursor, const unsigned* __restrict__ pairs,
    unsigned* __restrict__ colsp, int* __restrict__ count,
    int* __restrict__ row_start, float* __restrict__ dinv,
    unsigned short* __restrict__ xwb, int n_nodes) {
  __shared__ unsigned lpair[CAP];  // 10 KB
  __shared__ int hist[BROWS];
  __shared__ int scn[BROWS];
  __shared__ float ldinv[BROWS];
  int tid = threadIdx.x;
  int b = blockIdx.x;
  size_t base = (size_t)b * CAP;
  int n_b = coarse_cursor[b];
  if (n_b > CAP) n_b = CAP;

  if (tid < BROWS) hist[tid] = 0;
  __syncthreads();

  for (int i = tid; i < n_b; i += 512) {  // copy + histogram in one pass
    unsigned p = pairs[base + i];
    lpair[i] = p;
    atomicAdd(&hist[p >> 17], 1);
  }
  __syncthreads();

  if (tid < BROWS) scn[tid] = hist[tid];
  __syncthreads();
  for (int off = 1; off < BROWS; off <<= 1) {
    int t = (tid >= off && tid < BROWS) ? scn[tid - off] : 0;
    __syncthreads();
    if (tid < BROWS) scn[tid] += t;
    __syncthreads();
  }

  if (tid < BROWS) {
    int e = (tid > 0) ? scn[tid - 1] : 0;
    int r = b * BROWS + tid;
    if (r < n_nodes) {
      int deg = hist[tid];
      float d = rsqrtf((float)deg + 1.0f);
      count[r] = deg;
      row_start[r] = (int)base + e;
      dinv[r] = d;
      ldinv[tid] = d;
    }
    hist[tid] = e;  // becomes scatter cursor
  }
  __syncthreads();

  for (int i = tid; i < n_b; i += 512) {
    unsigned p = lpair[i];
    int slot = atomicAdd(&hist[p >> 17], 1);
    colsp[base + slot] = p & 0x1FFFFu;
  }

  // scale xwb rows of this bucket: xwb[r] *= dinv[r]  (4 threads/row x 16ch)
  {
    int rl = tid >> 2;
    int ch = (tid & 3) * 16;
    int r = b * BROWS + rl;
    if (r < n_nodes) {
      float dv = ldinv[rl];
      unsigned short* p = xwb + (size_t)r * OUT_SIZE + ch;
      short8 v0 = *(const short8*)(p);
      short8 v1 = *(const short8*)(p + 8);
      short8 o0, o1;
#pragma unroll
      for (int k = 0; k < 8; k++) {
        o0[k] = (short)f2bf(dv * bf2f((unsigned short)v0[k]));
        o1[k] = (short)f2bf(dv * bf2f((unsigned short)v1[k]));
      }
      *(short8*)(p) = o0;
      *(short8*)(p + 8) = o1;
    }
  }
}

// ---------------------------------------------------------------------------
// K3: CSR gather, round-3 structure with r0's weight scheme restored:
// xwb is pre-scaled by dinv[c], so the edge loop has NO dinv load --
// the serial chain is colsp -> xwb only. m = 1/0 activity mask.
__global__ __launch_bounds__(256) void gather_kernel(
    const int* __restrict__ row_start, const int* __restrict__ count,
    const unsigned* __restrict__ colsp, const float* __restrict__ dinv,
    const unsigned short* __restrict__ xwb, float* __restrict__ out,
    int n_nodes) {
  int lane = threadIdx.x & 63;
  int wave = threadIdx.x >> 6;
  int sub = lane & 7;   // edge slot
  int cg = lane >> 3;   // channels cg*8 .. cg*8+7
  int rb = (blockIdx.x * 4 + wave) * 4;  // first of 4 rows
  if (rb >= n_nodes) return;

  int start[4], cnt[4];
  int maxc = 0;
#pragma unroll
  for (int i = 0; i < 4; i++) {
    int r = rb + i;
    bool ok = r < n_nodes;
    start[i] = ok ? row_start[r] : 0;
    cnt[i] = ok ? count[r] : 0;
    maxc = max(maxc, cnt[i]);
  }

  float acc[4][8];
#pragma unroll
  for (int i = 0; i < 4; i++)
#pragma unroll
    for (int k = 0; k < 8; k++) acc[i][k] = 0.f;

  if (sub == 0) {  // self-loop terms: xwb[r] already = dinv[r]*xw[r]
#pragma unroll
    for (int i = 0; i < 4; i++) {
      int r = rb + i;
      if (r < n_nodes) {
        short8 v = *(const short8*)(xwb + (size_t)r * OUT_SIZE + cg * 8);
#pragma unroll
        for (int k = 0; k < 8; k++) acc[i][k] = bf2f((unsigned short)v[k]);
      }
    }
  }

  for (int j = 0; j < maxc; j += 8) {
    int c[4];
    float m[4];
    int idx = j + sub;
#pragma unroll
    for (int i = 0; i < 4; i++) {
      bool act = idx < cnt[i];
      c[i] = act ? (int)colsp[start[i] + idx] : rb;  // dummy -> hot line
      m[i] = act ? 1.0f : 0.0f;
    }
    short8 v[4];
#pragma unroll
    for (int i = 0; i < 4; i++)
      v[i] = *(const short8*)(xwb + (size_t)c[i] * OUT_SIZE + cg * 8);
#pragma unroll
    for (int i = 0; i < 4; i++)
#pragma unroll
      for (int k = 0; k < 8; k++)
        acc[i][k] += m[i] * bf2f((unsigned short)v[i][k]);
  }

#pragma unroll
  for (int i = 0; i < 4; i++)
#pragma unroll
    for (int k = 0; k < 8; k++) {
      acc[i][k] += __shfl_xor(acc[i][k], 1);
      acc[i][k] += __shfl_xor(acc[i][k], 2);
      acc[i][k] += __shfl_xor(acc[i][k], 4);
    }

  if (sub == 0) {
#pragma unroll
    for (int i = 0; i < 4; i++) {
      int r = rb + i;
      if (r < n_nodes) {
        float dr = dinv[r];
        float* dst = out + (size_t)r * OUT_SIZE + cg * 8;
        *(float4*)(dst) =
            make_float4(dr * acc[i][0], dr * acc[i][1], dr * acc[i][2],
                        dr * acc[i][3]);
        *(float4*)(dst + 4) =
            make_float4(dr * acc[i][4], dr * acc[i][5], dr * acc[i][6],
                        dr * acc[i][7]);
      }
    }
  }
}

// ---------------------------------------------------------------------------
extern "C" void kernel_launch(void* const* d_in, const int* in_sizes, int n_in,
                              void* d_out, int out_size, void* d_ws,
                              size_t ws_size, hipStream_t stream) {
  const int* edge_index = (const int*)d_in[0];
  const float* x = (const float*)d_in[1];
  const float* W = (const float*)d_in[3];

  int n_edges = in_sizes[0] / 2;
  int n_nodes = in_sizes[1] / IN_SIZE;
  const int* row = edge_index;
  const int* col = edge_index + n_edges;
  float* out = (float*)d_out;

  int nbuck = (n_nodes + BROWS - 1) >> BSHIFT;          // 782
  int nb_coarse = (n_edges + K1_EDGES - 1) / K1_EDGES;  // 391
  int nb_mm = (n_nodes + 127) / 128;                    // 782

  // Workspace: count[N] | row_start[N] | dinv[N] | coarse_cursor(4KB) |
  //            pairs[nbuck*CAP u32] | colsp[nbuck*CAP u32] | xwb[N*64 bf16]
  char* ws = (char*)d_ws;
  size_t nb4 = ((size_t)n_nodes * 4 + 15) & ~(size_t)15;
  int* count = (int*)ws;
  int* row_start = (int*)(ws + nb4);
  float* dinv = (float*)(ws + 2 * nb4);
  int* coarse_cursor = (int*)(ws + 3 * nb4);
  size_t pairsB = (size_t)nbuck * CAP * 4;  // 8,007,680 B
  unsigned* pairs = (unsigned*)(ws + 3 * nb4 + 4096);
  unsigned* colsp = (unsigned*)(ws + 3 * nb4 + 4096 + pairsB);
  unsigned short* xwb =
      (unsigned short*)(ws + 3 * nb4 + 4096 + 2 * pairsB);

  zero_kernel<<<2, 512, 0, stream>>>(coarse_cursor);
  fused1_kernel<<<nb_coarse + nb_mm, 512, 0, stream>>>(
      row, col, coarse_cursor, pairs, x, W, xwb, n_edges, n_nodes, nbuck,
      nb_coarse);
  fine_kernel<<<nbuck, 512, 0, stream>>>(coarse_cursor, pairs, colsp, count,
                                         row_start, dinv, xwb, n_nodes);
  gather_kernel<<<(n_nodes + 15) / 16, 256, 0, stream>>>(
      row_start, count, colsp, dinv, xwb, out, n_nodes);
}